// Round 12
// baseline (170.331 us; speedup 1.0000x reference)
//
#include <hip/hip_runtime.h>
#include <math.h>

#define Hh 128
#define Ww 128
#define HW (128*128)
#define PITCH 130
#define PADPX (130*130)

typedef unsigned short u16;
typedef unsigned int uint;
typedef _Float16 f16;
typedef __attribute__((ext_vector_type(8))) _Float16 f16x8;
typedef __attribute__((ext_vector_type(4))) float f32x4;

// ---------------- zero halo edges of padded NHWC f16 buffer ----------------
__global__ __launch_bounds__(256) void zero_edge_k(u16* __restrict__ buf, int cu16) {
  int per_px = cu16 >> 3;
  int total = 516 * per_px;
  int idx = blockIdx.x * 256 + threadIdx.x;
  int b = blockIdx.y;
  if (idx >= total) return;
  int e = idx / per_px, q = idx - e * per_px;
  int y, x;
  if (e < 130)      { y = 0;   x = e; }
  else if (e < 260) { y = 129; x = e - 130; }
  else { int j = e - 260; y = 1 + (j >> 1); x = (j & 1) ? 129 : 0; }
  *(uint4*)&buf[((size_t)b * PADPX + (size_t)(y * PITCH + x)) * cu16 + q * 8] =
      make_uint4(0, 0, 0, 0);
}

// ---------------- prep: cond [B][133][HW] f32 -> padded NHWC f16 [B][PADPX][160] ----------------
__global__ __launch_bounds__(256) void prep_cond_k(const float* __restrict__ cond,
                                                   f16* __restrict__ out) {
  int p = blockIdx.x * 256 + threadIdx.x;
  int b = blockIdx.y;
  int y = p >> 7, x = p & 127;
  const float* cb = cond + (size_t)b * 133 * HW + p;
  f16* ob = out + ((size_t)b * PADPX + (size_t)((y + 1) * PITCH + x + 1)) * 160;
  for (int c = 0; c < 160; c += 8) {
    f16 buf[8];
    #pragma unroll
    for (int j = 0; j < 8; j++) {
      float v = (c + j < 133) ? cb[(size_t)(c + j) * HW] : 0.f;
      buf[j] = (f16)v;
    }
    *(uint4*)&ob[c] = *(uint4*)buf;
  }
}

// ---------------- conv weight -> f16 MFMA A-frags: frag = (t*NC + c)*NCOF + f ----------------
__global__ __launch_bounds__(256) void wtrans_mfma_k(const float* __restrict__ w,
                                                     f16* __restrict__ wt,
                                                     int CIN, int NC, int NCOF) {
  int idx = blockIdx.x * 256 + threadIdx.x;
  int total = 9 * NC * NCOF * 64;
  if (idx >= total) return;
  int lane = idx & 63;
  int frag = idx >> 6;
  int f = frag % NCOF;
  int rest = frag / NCOF;
  int c = rest % NC;
  int t = rest / NC;
  int co = f * 16 + (lane & 15);
  int ci0 = c * 32 + (lane >> 4) * 8;
  f16 buf[8];
  #pragma unroll
  for (int j = 0; j < 8; j++) {
    int ci = ci0 + j;
    buf[j] = (f16)((ci < CIN) ? w[((size_t)co * CIN + ci) * 9 + t] : 0.f);
  }
  *(uint4*)&wt[(size_t)idx * 8] = *(uint4*)buf;
}

// ---------------- dcn weight -> f16 A-frags over K=576 (ci = k*64 + dg*4 + c) ----------------
__global__ __launch_bounds__(256) void wtrans_dcn_mfma_k(const float* __restrict__ w,
                                                         f16* __restrict__ wt) {
  int idx = blockIdx.x * 256 + threadIdx.x;
  if (idx >= 18 * 4 * 64) return;
  int lane = idx & 63;
  int frag = idx >> 6;
  int f = frag & 3;
  int chunk = frag >> 2;
  int co = f * 16 + (lane & 15);
  int ci0 = chunk * 32 + (lane >> 4) * 8;
  f16 buf[8];
  #pragma unroll
  for (int j = 0; j < 8; j++) {
    int ci = ci0 + j;
    int k = ci >> 6, cig = ci & 63;
    buf[j] = (f16)w[((size_t)co * 64 + cig) * 9 + k];
  }
  *(uint4*)&wt[(size_t)idx * 8] = *(uint4*)buf;
}

// x [B][64][H][W] f32 -> xt2 [B][16][H][W][8] f16 : (4ch @ x, 4ch @ min(x+1,127))
__global__ __launch_bounds__(256) void xtrans2_k(const float* __restrict__ x,
                                                 f16* __restrict__ xt2, int B) {
  int idx = blockIdx.x * 256 + threadIdx.x;
  int total = B * 16 * HW;
  if (idx >= total) return;
  int b = idx / (16 * HW);
  int r = idx % (16 * HW);
  int dg = r / HW, p = r % HW;
  int y = p >> 7, xx = p & 127;
  int x1 = min(xx + 1, 127);
  const float* xb = x + ((size_t)b * 64 + dg * 4) * HW + (size_t)y * Ww;
  f16 o[8];
  #pragma unroll
  for (int c = 0; c < 4; c++) {
    o[c] = (f16)xb[(size_t)c * HW + xx];
    o[4 + c] = (f16)xb[(size_t)c * HW + x1];
  }
  *(uint4*)&xt2[(size_t)idx * 8] = *(uint4*)o;
}

// ---------------- conv3x3 via f16 MFMA, 16x8 tile, LDS-staged (round-8 structure) ----------
// EPI==2 writes packed offm[b][dg][k][px] = (dy, dx, m, pad) f32 16B slots.
template<int CINP, int NC, int NCF, int NCOF, int EPI>
__global__ __launch_bounds__(256) void conv_f16_k(
    const f16* __restrict__ in, const f16* __restrict__ wt,
    const float* __restrict__ bias, f16* __restrict__ out,
    float* __restrict__ offm, const float* __restrict__ flow, int cogroups)
{
  __shared__ u16 lds[180 * 40];
  const int tid = threadIdx.x;
  const int lane = tid & 63, wave = tid >> 6;
  const int b = blockIdx.z / cogroups, cog = blockIdx.z % cogroups;
  const int gx0 = blockIdx.x * 16, gy0 = blockIdx.y * 8;

  f32x4 acc[2][NCF];
  #pragma unroll
  for (int i = 0; i < 2; i++)
    #pragma unroll
    for (int j = 0; j < NCF; j++) acc[i][j] = (f32x4)0.f;

  const f16* inb = in + (size_t)b * PADPX * CINP;

  for (int c = 0; c < NC; c++) {
    __syncthreads();
    for (int i = tid; i < 720; i += 256) {
      int pidx = i >> 2, q = i & 3;
      int py = pidx / 18, px = pidx - py * 18;
      size_t gp = (size_t)((gy0 + py) * PITCH + gx0 + px);
      uint4 v = *(const uint4*)&inb[gp * CINP + c * 32 + q * 8];
      *(uint4*)&lds[pidx * 40 + q * 8] = v;
    }
    __syncthreads();

    #pragma unroll
    for (int tap = 0; tap < 9; tap++) {
      const int dy = tap / 3, dx = tap % 3;
      f16x8 bfrag[2];
      #pragma unroll
      for (int pl = 0; pl < 2; pl++) {
        int pidx_r = (wave * 2 + pl + dy) * 18 + (lane & 15) + dx;
        bfrag[pl] = *(const f16x8*)&lds[pidx_r * 40 + (lane >> 4) * 8];
      }
      const f16* fA = wt + (((size_t)(tap * NC + c)) * NCOF + cog * NCF) * 512
                      + (size_t)lane * 8;
      #pragma unroll
      for (int cf = 0; cf < NCF; cf++) {
        f16x8 a = *(const f16x8*)&fA[(size_t)cf * 512];
        #pragma unroll
        for (int pl = 0; pl < 2; pl++)
          acc[pl][cf] = __builtin_amdgcn_mfma_f32_16x16x32_f16(a, bfrag[pl], acc[pl][cf], 0, 0, 0);
      }
    }
  }

  const int co_l = (lane >> 4) * 4;
  if (EPI == 0) {
    #pragma unroll
    for (int pl = 0; pl < 2; pl++) {
      size_t pp = (size_t)((gy0 + wave * 2 + pl + 1) * PITCH + gx0 + (lane & 15) + 1);
      f16* ob = out + ((size_t)b * PADPX + pp) * (NCOF * 16);
      #pragma unroll
      for (int cf = 0; cf < NCF; cf++) {
        int c0 = (cog * NCF + cf) * 16 + co_l;
        f16 buf[4];
        #pragma unroll
        for (int r = 0; r < 4; r++) {
          float v = acc[pl][cf][r] + bias[c0 + r];
          buf[r] = (f16)((v >= 0.f) ? v : 0.1f * v);
        }
        *(uint2*)&ob[c0] = *(uint2*)buf;
      }
    }
  } else {
    #pragma unroll
    for (int pl = 0; pl < 2; pl++) {
      size_t pix = (size_t)(gy0 + wave * 2 + pl) * Ww + gx0 + (lane & 15);
      float fl0 = flow[((size_t)b * 2 + 0) * HW + pix];
      float fl1 = flow[((size_t)b * 2 + 1) * HW + pix];
      #pragma unroll
      for (int cf = 0; cf < NCF; cf++) {
        int c0 = (cog * NCF + cf) * 16 + co_l;
        if (c0 < 288) {
          float v[4];
          #pragma unroll
          for (int r = 0; r < 4; r++) {
            float vv = acc[pl][cf][r] + bias[c0 + r];
            float e = __expf(2.f * vv);
            float t = 1.f - 2.f * __builtin_amdgcn_rcpf(e + 1.f);
            v[r] = 10.f * t + (((c0 + r) & 1) ? fl0 : fl1);
          }
          int dg0 = c0 / 18, j0 = c0 % 18;
          int tA = j0 >> 1;
          float* sA = offm + ((((size_t)b * 16 + dg0) * 9 + tA) * HW + pix) * 4;
          *(float2*)sA = make_float2(v[0], v[1]);
          int j2 = j0 + 2;
          int dgB = (j2 >= 18) ? dg0 + 1 : dg0;
          int tB  = (j2 >= 18) ? 0 : (j2 >> 1);
          float* sB = offm + ((((size_t)b * 16 + dgB) * 9 + tB) * HW + pix) * 4;
          *(float2*)sB = make_float2(v[2], v[3]);
        } else {
          #pragma unroll
          for (int r = 0; r < 4; r++) {
            int cm = c0 + r - 288;
            int dg = cm / 9, t = cm % 9;
            float vv = acc[pl][cf][r] + bias[c0 + r];
            offm[((((size_t)b * 16 + dg) * 9 + t) * HW + pix) * 4 + 2] =
                __builtin_amdgcn_rcpf(1.f + __expf(-vv));
          }
        }
      }
    }
  }
}

// ---------------- fused dcn: wave-local, barrier-free, packed-aux, 2-slot pipeline --------
// lane l: px = px0 + (l&15), qg = l>>4; task t -> dg = (t>>1)*8 + qg*2 + (t&1).
// aux = one float4 (dy,dx,m,pad) per sample, coalesced.
__global__ __launch_bounds__(256) void dcn_fused_k(
    const f16* __restrict__ xt2, const float* __restrict__ offm,
    const f16* __restrict__ wtd, const float* __restrict__ bias,
    float* __restrict__ out)
{
  const int lane = threadIdx.x & 63, wave = threadIdx.x >> 6;
  const int bid = blockIdx.x;
  const int nid = (bid & 7) * 64 + (bid >> 3);   // bijective XCD swizzle (512 = 8*64)
  const int tile = nid * 4 + wave;               // 0..2047
  const int b = tile >> 10;
  const int px0 = (tile & 1023) * 16;
  const int pxl = lane & 15;
  const int px = px0 + pxl;
  const int y = px >> 7, x0i = px & 127;
  const int qg = lane >> 4;

  const float* auxbase = offm + ((size_t)b * 144 * HW + px) * 4;
  const f16* xbase = xt2 + (size_t)b * 16 * ((size_t)HW * 8);

  f32x4 acc0 = (f32x4)0.f, acc1 = (f32x4)0.f, acc2 = (f32x4)0.f, acc3 = (f32x4)0.f;

  float4 auxn[4];
  float wgt[2][4][4];
  int   hs[2][4];
  f16x8 gA[2][4], gB[2][4];

#define DGOF(t) (((t) >> 1) * 8 + qg * 2 + ((t) & 1))

#define AUXL(kk) { _Pragma("unroll") for (int t = 0; t < 4; t++) { \
    auxn[t] = *(const float4*)&auxbase[(size_t)(DGOF(t) * 9 + (kk)) * (HW * 4)]; } }

#define GATH(sl, kk) { _Pragma("unroll") for (int t = 0; t < 4; t++) { \
    int dg = DGOF(t); \
    float py  = (float)(y - 1 + (kk) / 3) + auxn[t].x; \
    float pxx = (float)(x0i - 1 + (kk) % 3) + auxn[t].y; \
    float mv  = auxn[t].z; \
    float y0f = floorf(py), x0f = floorf(pxx); \
    float wy = py - y0f, wx = pxx - x0f; \
    int yi = (int)y0f, xi = (int)x0f; \
    bool vy0 = (yi >= 0) & (yi < Hh); \
    bool vy1 = (yi + 1 >= 0) & (yi + 1 < Hh); \
    bool vx0 = (xi >= 0) & (xi < Ww); \
    bool vx1 = (xi + 1 >= 0) & (xi + 1 < Ww); \
    int y0c = min(max(yi, 0), Hh - 1), y1c = min(max(yi + 1, 0), Hh - 1); \
    int xb = min(max(xi, 0), Ww - 1); \
    hs[sl][t] = min(max(xi + 1, 0), Ww - 1) - xb; \
    wgt[sl][t][0] = (vy0 && vx0) ? (1.f - wy) * (1.f - wx) * mv : 0.f; \
    wgt[sl][t][1] = (vy0 && vx1) ? (1.f - wy) * wx * mv : 0.f; \
    wgt[sl][t][2] = (vy1 && vx0) ? wy * (1.f - wx) * mv : 0.f; \
    wgt[sl][t][3] = (vy1 && vx1) ? wy * wx * mv : 0.f; \
    const f16* xp = xbase + (size_t)dg * ((size_t)HW * 8); \
    gA[sl][t] = *(const f16x8*)&xp[(size_t)(y0c * Ww + xb) * 8]; \
    gB[sl][t] = *(const f16x8*)&xp[(size_t)(y1c * Ww + xb) * 8]; } }

#define BLEND(sl, kk) { f16 bfa[2][8]; \
  _Pragma("unroll") for (int t = 0; t < 4; t++) { \
    _Pragma("unroll") for (int c = 0; c < 4; c++) { \
      float a00 = (float)gA[sl][t][c]; \
      float a01 = hs[sl][t] ? (float)gA[sl][t][4 + c] : (float)gA[sl][t][c]; \
      float a10 = (float)gB[sl][t][c]; \
      float a11 = hs[sl][t] ? (float)gB[sl][t][4 + c] : (float)gB[sl][t][c]; \
      bfa[t >> 1][(t & 1) * 4 + c] = (f16)(a00 * wgt[sl][t][0] + a01 * wgt[sl][t][1] \
                                         + a10 * wgt[sl][t][2] + a11 * wgt[sl][t][3]); } } \
  f16x8 bf0 = *(const f16x8*)&bfa[0][0]; \
  f16x8 bf1 = *(const f16x8*)&bfa[1][0]; \
  const f16* wc0 = wtd + ((size_t)(((kk) * 2 + 0) * 4) * 64 + (size_t)lane) * 8; \
  const f16* wc1 = wtd + ((size_t)(((kk) * 2 + 1) * 4) * 64 + (size_t)lane) * 8; \
  acc0 = __builtin_amdgcn_mfma_f32_16x16x32_f16(*(const f16x8*)&wc0[0],    bf0, acc0, 0, 0, 0); \
  acc1 = __builtin_amdgcn_mfma_f32_16x16x32_f16(*(const f16x8*)&wc0[512],  bf0, acc1, 0, 0, 0); \
  acc2 = __builtin_amdgcn_mfma_f32_16x16x32_f16(*(const f16x8*)&wc0[1024], bf0, acc2, 0, 0, 0); \
  acc3 = __builtin_amdgcn_mfma_f32_16x16x32_f16(*(const f16x8*)&wc0[1536], bf0, acc3, 0, 0, 0); \
  acc0 = __builtin_amdgcn_mfma_f32_16x16x32_f16(*(const f16x8*)&wc1[0],    bf1, acc0, 0, 0, 0); \
  acc1 = __builtin_amdgcn_mfma_f32_16x16x32_f16(*(const f16x8*)&wc1[512],  bf1, acc1, 0, 0, 0); \
  acc2 = __builtin_amdgcn_mfma_f32_16x16x32_f16(*(const f16x8*)&wc1[1024], bf1, acc2, 0, 0, 0); \
  acc3 = __builtin_amdgcn_mfma_f32_16x16x32_f16(*(const f16x8*)&wc1[1536], bf1, acc3, 0, 0, 0); }

  // software pipeline: aux 1 tap ahead, gathers 1 tap ahead of blend
  AUXL(0); GATH(0, 0); AUXL(1);
  GATH(1, 1); AUXL(2); BLEND(0, 0);
  GATH(0, 2); AUXL(3); BLEND(1, 1);
  GATH(1, 3); AUXL(4); BLEND(0, 2);
  GATH(0, 4); AUXL(5); BLEND(1, 3);
  GATH(1, 5); AUXL(6); BLEND(0, 4);
  GATH(0, 6); AUXL(7); BLEND(1, 5);
  GATH(1, 7); AUXL(8); BLEND(0, 6);
  GATH(0, 8);          BLEND(1, 7);
                       BLEND(0, 8);

  // epilogue: out[b][co][px], co = f*16 + qg*4 + r
  float* ob = out + (size_t)b * 64 * HW + px0 + pxl;
  #pragma unroll
  for (int r = 0; r < 4; r++) {
    int c0 = qg * 4 + r;
    ob[(size_t)(c0) * HW]      = acc0[r] + bias[c0];
    ob[(size_t)(c0 + 16) * HW] = acc1[r] + bias[c0 + 16];
    ob[(size_t)(c0 + 32) * HW] = acc2[r] + bias[c0 + 32];
    ob[(size_t)(c0 + 48) * HW] = acc3[r] + bias[c0 + 48];
  }
#undef DGOF
#undef AUXL
#undef GATH
#undef BLEND
}

// ---------------- launch ----------------
extern "C" void kernel_launch(void* const* d_in, const int* in_sizes, int n_in,
                              void* d_out, int out_size, void* d_ws, size_t ws_size,
                              hipStream_t stream) {
  const float* x    = (const float*)d_in[0];
  const float* cond = (const float*)d_in[1];
  const float* flow = (const float*)d_in[2];
  const float* w1 = (const float*)d_in[3];
  const float* b1 = (const float*)d_in[4];
  const float* w2 = (const float*)d_in[5];
  const float* b2 = (const float*)d_in[6];
  const float* w3 = (const float*)d_in[7];
  const float* b3 = (const float*)d_in[8];
  const float* w4 = (const float*)d_in[9];
  const float* b4 = (const float*)d_in[10];
  const float* wD = (const float*)d_in[11];
  const float* bD = (const float*)d_in[12];
  float* out = (float*)d_out;
  const int B = 2;

  char* ws = (char*)d_ws;
  f16* condp = (f16*)ws;                         // 10,816,000
  f16* hA = (f16*)(ws + 10816000);               //  4,326,400
  f16* hB = (f16*)(ws + 15142400);               //  4,326,400
  char* pw = ws + 19468800;
  float* offm = (float*)pw;          pw += 75497472;  // [B][16][9][HW] x 16B
  f16*   xt2  = (f16*)pw;            pw += 8388608;
  f16*   wt1  = (f16*)pw;            pw += 184320;
  f16*   wt2  = (f16*)pw;            pw += 73728;
  f16*   wt3  = (f16*)pw;            pw += 73728;
  f16*   wt4  = (f16*)pw;            pw += 497664;
  f16*   wtd  = (f16*)pw;            pw += 73728;

  // halo zeroing + prep + weight transposes
  zero_edge_k<<<dim3((516 * 20 + 255) / 256, B), 256, 0, stream>>>((u16*)condp, 160);
  zero_edge_k<<<dim3((516 * 8 + 255) / 256, B), 256, 0, stream>>>((u16*)hA, 64);
  zero_edge_k<<<dim3((516 * 8 + 255) / 256, B), 256, 0, stream>>>((u16*)hB, 64);
  prep_cond_k<<<dim3(HW / 256, B), 256, 0, stream>>>(cond, condp);
  xtrans2_k<<<dim3(B * 16 * HW / 256), 256, 0, stream>>>(x, xt2, B);
  wtrans_mfma_k<<<dim3((9 * 5 * 4 * 64 + 255) / 256), 256, 0, stream>>>(w1, wt1, 133, 5, 4);
  wtrans_mfma_k<<<dim3((9 * 2 * 4 * 64 + 255) / 256), 256, 0, stream>>>(w2, wt2, 64, 2, 4);
  wtrans_mfma_k<<<dim3((9 * 2 * 4 * 64 + 255) / 256), 256, 0, stream>>>(w3, wt3, 64, 2, 4);
  wtrans_mfma_k<<<dim3((9 * 2 * 27 * 64 + 255) / 256), 256, 0, stream>>>(w4, wt4, 64, 2, 27);
  wtrans_dcn_mfma_k<<<dim3((18 * 4 * 64 + 255) / 256), 256, 0, stream>>>(wD, wtd);

  // convs (f16 MFMA, 16x8 tiles, round-8 staging); conv4 writes packed offm
  conv_f16_k<160, 5, 1, 4, 0><<<dim3(8, 16, B * 4), 256, 0, stream>>>(
      condp, wt1, b1, hA, nullptr, nullptr, 4);
  conv_f16_k<64, 2, 1, 4, 0><<<dim3(8, 16, B * 4), 256, 0, stream>>>(
      hA, wt2, b2, hB, nullptr, nullptr, 4);
  conv_f16_k<64, 2, 1, 4, 0><<<dim3(8, 16, B * 4), 256, 0, stream>>>(
      hB, wt3, b3, hA, nullptr, nullptr, 4);
  conv_f16_k<64, 2, 3, 27, 2><<<dim3(8, 16, B * 9), 256, 0, stream>>>(
      hA, wt4, b4, nullptr, offm, flow, 9);

  // fused deformable conv: wave-local, packed-aux, 2-slot pipeline
  dcn_fused_k<<<dim3(512), 256, 0, stream>>>(xt2, offm, wtd, bD, out);
}

// Round 13
// 153.394 us; speedup vs baseline: 1.1104x; 1.1104x over previous
//
#include <hip/hip_runtime.h>
#include <math.h>

#define Hh 128
#define Ww 128
#define HW (128*128)
#define PITCH 130
#define PADPX (130*130)

typedef unsigned short u16;
typedef unsigned int uint;
typedef _Float16 f16;
typedef __attribute__((ext_vector_type(8))) _Float16 f16x8;
typedef __attribute__((ext_vector_type(4))) float f32x4;

// ---------------- zero halo edges of padded NHWC f16 buffer ----------------
__global__ __launch_bounds__(256) void zero_edge_k(u16* __restrict__ buf, int cu16) {
  int per_px = cu16 >> 3;
  int total = 516 * per_px;
  int idx = blockIdx.x * 256 + threadIdx.x;
  int b = blockIdx.y;
  if (idx >= total) return;
  int e = idx / per_px, q = idx - e * per_px;
  int y, x;
  if (e < 130)      { y = 0;   x = e; }
  else if (e < 260) { y = 129; x = e - 130; }
  else { int j = e - 260; y = 1 + (j >> 1); x = (j & 1) ? 129 : 0; }
  *(uint4*)&buf[((size_t)b * PADPX + (size_t)(y * PITCH + x)) * cu16 + q * 8] =
      make_uint4(0, 0, 0, 0);
}

// ---------------- prep: cond [B][133][HW] f32 -> padded NHWC f16 [B][PADPX][160] ----------------
__global__ __launch_bounds__(256) void prep_cond_k(const float* __restrict__ cond,
                                                   f16* __restrict__ out) {
  int p = blockIdx.x * 256 + threadIdx.x;
  int b = blockIdx.y;
  int y = p >> 7, x = p & 127;
  const float* cb = cond + (size_t)b * 133 * HW + p;
  f16* ob = out + ((size_t)b * PADPX + (size_t)((y + 1) * PITCH + x + 1)) * 160;
  for (int c = 0; c < 160; c += 8) {
    f16 buf[8];
    #pragma unroll
    for (int j = 0; j < 8; j++) {
      float v = (c + j < 133) ? cb[(size_t)(c + j) * HW] : 0.f;
      buf[j] = (f16)v;
    }
    *(uint4*)&ob[c] = *(uint4*)buf;
  }
}

// ---------------- conv weight -> f16 MFMA A-frags: frag = (t*NC + c)*NCOF + f ----------------
__global__ __launch_bounds__(256) void wtrans_mfma_k(const float* __restrict__ w,
                                                     f16* __restrict__ wt,
                                                     int CIN, int NC, int NCOF) {
  int idx = blockIdx.x * 256 + threadIdx.x;
  int total = 9 * NC * NCOF * 64;
  if (idx >= total) return;
  int lane = idx & 63;
  int frag = idx >> 6;
  int f = frag % NCOF;
  int rest = frag / NCOF;
  int c = rest % NC;
  int t = rest / NC;
  int co = f * 16 + (lane & 15);
  int ci0 = c * 32 + (lane >> 4) * 8;
  f16 buf[8];
  #pragma unroll
  for (int j = 0; j < 8; j++) {
    int ci = ci0 + j;
    buf[j] = (f16)((ci < CIN) ? w[((size_t)co * CIN + ci) * 9 + t] : 0.f);
  }
  *(uint4*)&wt[(size_t)idx * 8] = *(uint4*)buf;
}

// ---------------- dcn weight -> f16 A-frags over K=576 (ci = k*64 + dg*4 + c) ----------------
__global__ __launch_bounds__(256) void wtrans_dcn_mfma_k(const float* __restrict__ w,
                                                         f16* __restrict__ wt) {
  int idx = blockIdx.x * 256 + threadIdx.x;
  if (idx >= 18 * 4 * 64) return;
  int lane = idx & 63;
  int frag = idx >> 6;
  int f = frag & 3;
  int chunk = frag >> 2;
  int co = f * 16 + (lane & 15);
  int ci0 = chunk * 32 + (lane >> 4) * 8;
  f16 buf[8];
  #pragma unroll
  for (int j = 0; j < 8; j++) {
    int ci = ci0 + j;
    int k = ci >> 6, cig = ci & 63;
    buf[j] = (f16)w[((size_t)co * 64 + cig) * 9 + k];
  }
  *(uint4*)&wt[(size_t)idx * 8] = *(uint4*)buf;
}

// x [B][64][H][W] f32 -> xt2 [B][16][H][W][8] f16 : (4ch @ x, 4ch @ min(x+1,127))
__global__ __launch_bounds__(256) void xtrans2_k(const float* __restrict__ x,
                                                 f16* __restrict__ xt2, int B) {
  int idx = blockIdx.x * 256 + threadIdx.x;
  int total = B * 16 * HW;
  if (idx >= total) return;
  int b = idx / (16 * HW);
  int r = idx % (16 * HW);
  int dg = r / HW, p = r % HW;
  int y = p >> 7, xx = p & 127;
  int x1 = min(xx + 1, 127);
  const float* xb = x + ((size_t)b * 64 + dg * 4) * HW + (size_t)y * Ww;
  f16 o[8];
  #pragma unroll
  for (int c = 0; c < 4; c++) {
    o[c] = (f16)xb[(size_t)c * HW + xx];
    o[4 + c] = (f16)xb[(size_t)c * HW + x1];
  }
  *(uint4*)&xt2[(size_t)idx * 8] = *(uint4*)o;
}

// ---------------- conv3x3 via f16 MFMA, 16x8 tile, LDS-staged (round-8 structure) ----------
// EPI==2: offsets -> dense float2 planes offp2[b][dg][tap][px]; mask -> f16 plane mskb.
template<int CINP, int NC, int NCF, int NCOF, int EPI>
__global__ __launch_bounds__(256) void conv_f16_k(
    const f16* __restrict__ in, const f16* __restrict__ wt,
    const float* __restrict__ bias, f16* __restrict__ out,
    float* __restrict__ offp2, f16* __restrict__ mskb,
    const float* __restrict__ flow, int cogroups)
{
  __shared__ u16 lds[180 * 40];
  const int tid = threadIdx.x;
  const int lane = tid & 63, wave = tid >> 6;
  const int b = blockIdx.z / cogroups, cog = blockIdx.z % cogroups;
  const int gx0 = blockIdx.x * 16, gy0 = blockIdx.y * 8;

  f32x4 acc[2][NCF];
  #pragma unroll
  for (int i = 0; i < 2; i++)
    #pragma unroll
    for (int j = 0; j < NCF; j++) acc[i][j] = (f32x4)0.f;

  const f16* inb = in + (size_t)b * PADPX * CINP;

  for (int c = 0; c < NC; c++) {
    __syncthreads();
    for (int i = tid; i < 720; i += 256) {
      int pidx = i >> 2, q = i & 3;
      int py = pidx / 18, px = pidx - py * 18;
      size_t gp = (size_t)((gy0 + py) * PITCH + gx0 + px);
      uint4 v = *(const uint4*)&inb[gp * CINP + c * 32 + q * 8];
      *(uint4*)&lds[pidx * 40 + q * 8] = v;
    }
    __syncthreads();

    #pragma unroll
    for (int tap = 0; tap < 9; tap++) {
      const int dy = tap / 3, dx = tap % 3;
      f16x8 bfrag[2];
      #pragma unroll
      for (int pl = 0; pl < 2; pl++) {
        int pidx_r = (wave * 2 + pl + dy) * 18 + (lane & 15) + dx;
        bfrag[pl] = *(const f16x8*)&lds[pidx_r * 40 + (lane >> 4) * 8];
      }
      const f16* fA = wt + (((size_t)(tap * NC + c)) * NCOF + cog * NCF) * 512
                      + (size_t)lane * 8;
      #pragma unroll
      for (int cf = 0; cf < NCF; cf++) {
        f16x8 a = *(const f16x8*)&fA[(size_t)cf * 512];
        #pragma unroll
        for (int pl = 0; pl < 2; pl++)
          acc[pl][cf] = __builtin_amdgcn_mfma_f32_16x16x32_f16(a, bfrag[pl], acc[pl][cf], 0, 0, 0);
      }
    }
  }

  const int co_l = (lane >> 4) * 4;
  if (EPI == 0) {
    #pragma unroll
    for (int pl = 0; pl < 2; pl++) {
      size_t pp = (size_t)((gy0 + wave * 2 + pl + 1) * PITCH + gx0 + (lane & 15) + 1);
      f16* ob = out + ((size_t)b * PADPX + pp) * (NCOF * 16);
      #pragma unroll
      for (int cf = 0; cf < NCF; cf++) {
        int c0 = (cog * NCF + cf) * 16 + co_l;
        f16 buf[4];
        #pragma unroll
        for (int r = 0; r < 4; r++) {
          float v = acc[pl][cf][r] + bias[c0 + r];
          buf[r] = (f16)((v >= 0.f) ? v : 0.1f * v);
        }
        *(uint2*)&ob[c0] = *(uint2*)buf;
      }
    }
  } else {
    #pragma unroll
    for (int pl = 0; pl < 2; pl++) {
      size_t pix = (size_t)(gy0 + wave * 2 + pl) * Ww + gx0 + (lane & 15);
      float fl0 = flow[((size_t)b * 2 + 0) * HW + pix];
      float fl1 = flow[((size_t)b * 2 + 1) * HW + pix];
      #pragma unroll
      for (int cf = 0; cf < NCF; cf++) {
        int c0 = (cog * NCF + cf) * 16 + co_l;
        if (c0 < 288) {
          // 4 consecutive offset channels = 2 (dy,dx) pairs; j0 = c0%18 is always even
          float v[4];
          #pragma unroll
          for (int r = 0; r < 4; r++) {
            float vv = acc[pl][cf][r] + bias[c0 + r];
            float e = __expf(2.f * vv);
            float t = 1.f - 2.f * __builtin_amdgcn_rcpf(e + 1.f);
            v[r] = 10.f * t + (((c0 + r) & 1) ? fl0 : fl1);
          }
          int dg0 = c0 / 18, j0 = c0 % 18;
          int tA = j0 >> 1;
          *(float2*)&offp2[((((size_t)b * 16 + dg0) * 9 + tA) * HW + pix) * 2] =
              make_float2(v[0], v[1]);
          int j2 = j0 + 2;
          int dgB = (j2 >= 18) ? dg0 + 1 : dg0;
          int tB  = (j2 >= 18) ? 0 : (j2 >> 1);
          *(float2*)&offp2[((((size_t)b * 16 + dgB) * 9 + tB) * HW + pix) * 2] =
              make_float2(v[2], v[3]);
        } else {
          #pragma unroll
          for (int r = 0; r < 4; r++) {
            float vv = acc[pl][cf][r] + bias[c0 + r];
            mskb[((size_t)b * 144 + (c0 + r - 288)) * HW + pix] =
                (f16)__builtin_amdgcn_rcpf(1.f + __expf(-vv));
          }
        }
      }
    }
  }
}

// ---------------- fused dcn: wave-local, barrier-free, float2-aux, 2-slot pipeline --------
// lane l: px = px0 + (l&15), qg = l>>4; task t -> dg = (t>>1)*8 + qg*2 + (t&1).
__global__ __launch_bounds__(256) void dcn_fused_k(
    const f16* __restrict__ xt2, const float* __restrict__ offp2,
    const f16* __restrict__ mskb, const f16* __restrict__ wtd,
    const float* __restrict__ bias, float* __restrict__ out)
{
  const int lane = threadIdx.x & 63, wave = threadIdx.x >> 6;
  const int bid = blockIdx.x;
  const int nid = (bid & 7) * 64 + (bid >> 3);   // bijective XCD swizzle (512 = 8*64)
  const int tile = nid * 4 + wave;               // 0..2047
  const int b = tile >> 10;
  const int px0 = (tile & 1023) * 16;
  const int pxl = lane & 15;
  const int px = px0 + pxl;
  const int y = px >> 7, x0i = px & 127;
  const int qg = lane >> 4;

  const float* o2base = offp2 + ((size_t)b * 144 * HW + px) * 2;
  const f16*   mbase  = mskb + (size_t)b * 144 * HW + px;
  const f16*   xbase  = xt2 + (size_t)b * 16 * ((size_t)HW * 8);

  f32x4 acc0 = (f32x4)0.f, acc1 = (f32x4)0.f, acc2 = (f32x4)0.f, acc3 = (f32x4)0.f;

  float2 auxn[4];
  float  mvn[4];
  float wgt[2][4][4];
  int   hs[2][4];
  f16x8 gA[2][4], gB[2][4];

#define DGOF(t) (((t) >> 1) * 8 + qg * 2 + ((t) & 1))

#define AUXL(kk) { _Pragma("unroll") for (int t = 0; t < 4; t++) { \
    auxn[t] = *(const float2*)&o2base[(size_t)(DGOF(t) * 9 + (kk)) * (HW * 2)]; \
    mvn[t]  = (float)mbase[(size_t)(DGOF(t) * 9 + (kk)) * HW]; } }

#define GATH(sl, kk) { _Pragma("unroll") for (int t = 0; t < 4; t++) { \
    int dg = DGOF(t); \
    float py  = (float)(y - 1 + (kk) / 3) + auxn[t].x; \
    float pxx = (float)(x0i - 1 + (kk) % 3) + auxn[t].y; \
    float mv  = mvn[t]; \
    float y0f = floorf(py), x0f = floorf(pxx); \
    float wy = py - y0f, wx = pxx - x0f; \
    int yi = (int)y0f, xi = (int)x0f; \
    bool vy0 = (yi >= 0) & (yi < Hh); \
    bool vy1 = (yi + 1 >= 0) & (yi + 1 < Hh); \
    bool vx0 = (xi >= 0) & (xi < Ww); \
    bool vx1 = (xi + 1 >= 0) & (xi + 1 < Ww); \
    int y0c = min(max(yi, 0), Hh - 1), y1c = min(max(yi + 1, 0), Hh - 1); \
    int xb = min(max(xi, 0), Ww - 1); \
    hs[sl][t] = min(max(xi + 1, 0), Ww - 1) - xb; \
    wgt[sl][t][0] = (vy0 && vx0) ? (1.f - wy) * (1.f - wx) * mv : 0.f; \
    wgt[sl][t][1] = (vy0 && vx1) ? (1.f - wy) * wx * mv : 0.f; \
    wgt[sl][t][2] = (vy1 && vx0) ? wy * (1.f - wx) * mv : 0.f; \
    wgt[sl][t][3] = (vy1 && vx1) ? wy * wx * mv : 0.f; \
    const f16* xp = xbase + (size_t)dg * ((size_t)HW * 8); \
    gA[sl][t] = *(const f16x8*)&xp[(size_t)(y0c * Ww + xb) * 8]; \
    gB[sl][t] = *(const f16x8*)&xp[(size_t)(y1c * Ww + xb) * 8]; } }

#define BLEND(sl, kk) { f16 bfa[2][8]; \
  _Pragma("unroll") for (int t = 0; t < 4; t++) { \
    _Pragma("unroll") for (int c = 0; c < 4; c++) { \
      float a00 = (float)gA[sl][t][c]; \
      float a01 = hs[sl][t] ? (float)gA[sl][t][4 + c] : (float)gA[sl][t][c]; \
      float a10 = (float)gB[sl][t][c]; \
      float a11 = hs[sl][t] ? (float)gB[sl][t][4 + c] : (float)gB[sl][t][c]; \
      bfa[t >> 1][(t & 1) * 4 + c] = (f16)(a00 * wgt[sl][t][0] + a01 * wgt[sl][t][1] \
                                         + a10 * wgt[sl][t][2] + a11 * wgt[sl][t][3]); } } \
  f16x8 bf0 = *(const f16x8*)&bfa[0][0]; \
  f16x8 bf1 = *(const f16x8*)&bfa[1][0]; \
  const f16* wc0 = wtd + ((size_t)(((kk) * 2 + 0) * 4) * 64 + (size_t)lane) * 8; \
  const f16* wc1 = wtd + ((size_t)(((kk) * 2 + 1) * 4) * 64 + (size_t)lane) * 8; \
  acc0 = __builtin_amdgcn_mfma_f32_16x16x32_f16(*(const f16x8*)&wc0[0],    bf0, acc0, 0, 0, 0); \
  acc1 = __builtin_amdgcn_mfma_f32_16x16x32_f16(*(const f16x8*)&wc0[512],  bf0, acc1, 0, 0, 0); \
  acc2 = __builtin_amdgcn_mfma_f32_16x16x32_f16(*(const f16x8*)&wc0[1024], bf0, acc2, 0, 0, 0); \
  acc3 = __builtin_amdgcn_mfma_f32_16x16x32_f16(*(const f16x8*)&wc0[1536], bf0, acc3, 0, 0, 0); \
  acc0 = __builtin_amdgcn_mfma_f32_16x16x32_f16(*(const f16x8*)&wc1[0],    bf1, acc0, 0, 0, 0); \
  acc1 = __builtin_amdgcn_mfma_f32_16x16x32_f16(*(const f16x8*)&wc1[512],  bf1, acc1, 0, 0, 0); \
  acc2 = __builtin_amdgcn_mfma_f32_16x16x32_f16(*(const f16x8*)&wc1[1024], bf1, acc2, 0, 0, 0); \
  acc3 = __builtin_amdgcn_mfma_f32_16x16x32_f16(*(const f16x8*)&wc1[1536], bf1, acc3, 0, 0, 0); }

  // software pipeline: aux 1 tap ahead, gathers 1 tap ahead of blend
  AUXL(0); GATH(0, 0); AUXL(1);
  GATH(1, 1); AUXL(2); BLEND(0, 0);
  GATH(0, 2); AUXL(3); BLEND(1, 1);
  GATH(1, 3); AUXL(4); BLEND(0, 2);
  GATH(0, 4); AUXL(5); BLEND(1, 3);
  GATH(1, 5); AUXL(6); BLEND(0, 4);
  GATH(0, 6); AUXL(7); BLEND(1, 5);
  GATH(1, 7); AUXL(8); BLEND(0, 6);
  GATH(0, 8);          BLEND(1, 7);
                       BLEND(0, 8);

  // epilogue: out[b][co][px], co = f*16 + qg*4 + r
  float* ob = out + (size_t)b * 64 * HW + px0 + pxl;
  #pragma unroll
  for (int r = 0; r < 4; r++) {
    int c0 = qg * 4 + r;
    ob[(size_t)(c0) * HW]      = acc0[r] + bias[c0];
    ob[(size_t)(c0 + 16) * HW] = acc1[r] + bias[c0 + 16];
    ob[(size_t)(c0 + 32) * HW] = acc2[r] + bias[c0 + 32];
    ob[(size_t)(c0 + 48) * HW] = acc3[r] + bias[c0 + 48];
  }
#undef DGOF
#undef AUXL
#undef GATH
#undef BLEND
}

// ---------------- launch ----------------
extern "C" void kernel_launch(void* const* d_in, const int* in_sizes, int n_in,
                              void* d_out, int out_size, void* d_ws, size_t ws_size,
                              hipStream_t stream) {
  const float* x    = (const float*)d_in[0];
  const float* cond = (const float*)d_in[1];
  const float* flow = (const float*)d_in[2];
  const float* w1 = (const float*)d_in[3];
  const float* b1 = (const float*)d_in[4];
  const float* w2 = (const float*)d_in[5];
  const float* b2 = (const float*)d_in[6];
  const float* w3 = (const float*)d_in[7];
  const float* b3 = (const float*)d_in[8];
  const float* w4 = (const float*)d_in[9];
  const float* b4 = (const float*)d_in[10];
  const float* wD = (const float*)d_in[11];
  const float* bD = (const float*)d_in[12];
  float* out = (float*)d_out;
  const int B = 2;

  char* ws = (char*)d_ws;
  f16* condp = (f16*)ws;                         // 10,816,000
  f16* hA = (f16*)(ws + 10816000);               //  4,326,400
  f16* hB = (f16*)(ws + 15142400);               //  4,326,400
  char* pw = ws + 19468800;
  float* offp2 = (float*)pw;         pw += 37748736;  // [B][16][9][HW] float2
  f16*   mskb  = (f16*)pw;           pw += 9437184;   // [B][144][HW] f16
  f16*   xt2   = (f16*)pw;           pw += 8388608;
  f16*   wt1   = (f16*)pw;           pw += 184320;
  f16*   wt2   = (f16*)pw;           pw += 73728;
  f16*   wt3   = (f16*)pw;           pw += 73728;
  f16*   wt4   = (f16*)pw;           pw += 497664;
  f16*   wtd   = (f16*)pw;           pw += 73728;

  // halo zeroing + prep + weight transposes
  zero_edge_k<<<dim3((516 * 20 + 255) / 256, B), 256, 0, stream>>>((u16*)condp, 160);
  zero_edge_k<<<dim3((516 * 8 + 255) / 256, B), 256, 0, stream>>>((u16*)hA, 64);
  zero_edge_k<<<dim3((516 * 8 + 255) / 256, B), 256, 0, stream>>>((u16*)hB, 64);
  prep_cond_k<<<dim3(HW / 256, B), 256, 0, stream>>>(cond, condp);
  xtrans2_k<<<dim3(B * 16 * HW / 256), 256, 0, stream>>>(x, xt2, B);
  wtrans_mfma_k<<<dim3((9 * 5 * 4 * 64 + 255) / 256), 256, 0, stream>>>(w1, wt1, 133, 5, 4);
  wtrans_mfma_k<<<dim3((9 * 2 * 4 * 64 + 255) / 256), 256, 0, stream>>>(w2, wt2, 64, 2, 4);
  wtrans_mfma_k<<<dim3((9 * 2 * 4 * 64 + 255) / 256), 256, 0, stream>>>(w3, wt3, 64, 2, 4);
  wtrans_mfma_k<<<dim3((9 * 2 * 27 * 64 + 255) / 256), 256, 0, stream>>>(w4, wt4, 64, 2, 27);
  wtrans_dcn_mfma_k<<<dim3((18 * 4 * 64 + 255) / 256), 256, 0, stream>>>(wD, wtd);

  // convs (f16 MFMA, 16x8 tiles, round-8 staging); conv4 writes dense float2 offp2 + f16 mskb
  conv_f16_k<160, 5, 1, 4, 0><<<dim3(8, 16, B * 4), 256, 0, stream>>>(
      condp, wt1, b1, hA, nullptr, nullptr, nullptr, 4);
  conv_f16_k<64, 2, 1, 4, 0><<<dim3(8, 16, B * 4), 256, 0, stream>>>(
      hA, wt2, b2, hB, nullptr, nullptr, nullptr, 4);
  conv_f16_k<64, 2, 1, 4, 0><<<dim3(8, 16, B * 4), 256, 0, stream>>>(
      hB, wt3, b3, hA, nullptr, nullptr, nullptr, 4);
  conv_f16_k<64, 2, 3, 27, 2><<<dim3(8, 16, B * 9), 256, 0, stream>>>(
      hA, wt4, b4, nullptr, offp2, mskb, flow, 9);

  // fused deformable conv: wave-local, float2 aux, 2-slot pipeline
  dcn_fused_k<<<dim3(512), 256, 0, stream>>>(xt2, offp2, mskb, wtd, bD, out);
}